// Round 2
// baseline (228.319 us; speedup 1.0000x reference)
//
#include <hip/hip_runtime.h>

typedef unsigned int u32;
typedef unsigned short u16;
typedef __attribute__((ext_vector_type(8))) short bf16x8;
typedef __attribute__((ext_vector_type(8))) u16 u16x8;
typedef __attribute__((ext_vector_type(4))) float f32x4;

#define AS1 __attribute__((address_space(1)))
#define AS3 __attribute__((address_space(3)))

__device__ __forceinline__ void gload_lds16(const void* g, void* l) {
  __builtin_amdgcn_global_load_lds((const AS1 u32*)g, (AS3 u32*)l, 16, 0, 0);
}

__device__ __forceinline__ u16 f2bf(float f) {
  union { float f; u32 u; } x; x.f = f;
  u32 u = x.u;
  return (u16)((u + 0x7fffu + ((u >> 16) & 1u)) >> 16);
}

// ---------------- convert fp32 -> bf16 (q,k,v,Wq,Wk,Wv,Wo packed contiguously) ---------
__global__ __launch_bounds__(256) void convert_all(
    const float* __restrict__ q, const float* __restrict__ k, const float* __restrict__ v,
    const float* __restrict__ wq, const float* __restrict__ wk,
    const float* __restrict__ wv, const float* __restrict__ wo,
    u16* __restrict__ dst)
{
  int b = blockIdx.x, t = threadIdx.x;
  const float* sp; size_t lb;
  if (b < 6144) {
    sp = (b < 2048) ? q : ((b < 4096) ? k : v);
    lb = (size_t)(b & 2047) * 2048;
  } else {
    int w = (b - 6144) >> 9;
    sp = (w == 0) ? wq : ((w == 1) ? wk : ((w == 2) ? wv : wo));
    lb = (size_t)((b - 6144) & 511) * 2048;
  }
  lb += (size_t)t * 8;
  f32x4 f0 = *(const f32x4*)(sp + lb);
  f32x4 f1 = *(const f32x4*)(sp + lb + 4);
  u16x8 o;
  o[0]=f2bf(f0[0]); o[1]=f2bf(f0[1]); o[2]=f2bf(f0[2]); o[3]=f2bf(f0[3]);
  o[4]=f2bf(f1[0]); o[5]=f2bf(f1[1]); o[6]=f2bf(f1[2]); o[7]=f2bf(f1[3]);
  *(u16x8*)(dst + (size_t)b*2048 + (size_t)t*8) = o;
}

// ---------------- GEMM: C[M,N] = A[M,K] * B[N,K]^T + bias, bf16 in, OUT_T out ----------
// BM=128 BN=64 BK=64, 256 threads (4 waves, 2x2), wave tile 64x32.
template<typename OUT_T>
__global__ __launch_bounds__(256) void gemm_nt(
    const u16* __restrict__ A, const u16* __restrict__ Bw,
    const float* __restrict__ bias, OUT_T* __restrict__ C,
    int M, int N, int K)
{
  __shared__ __align__(16) u16 As[128*64];
  __shared__ __align__(16) u16 Bs[64*64];
  const int t = threadIdx.x;
  const int wid = t >> 6, l = t & 63;
  const int l4 = l >> 4, l15 = l & 15;
  const int m0 = blockIdx.y * 128, n0 = blockIdx.x * 64;
  const int wr = wid >> 1, wc = wid & 1;
  const int arow = t >> 3, achk = t & 7;

  f32x4 acc[4][2] = {};

  for (int k0 = 0; k0 < K; k0 += 64) {
    __syncthreads();
#pragma unroll
    for (int i = 0; i < 4; ++i) {
      int row = i*32 + arow;
      gload_lds16(A + (size_t)(m0+row)*K + k0 + ((achk ^ (row&7)) << 3),
                  &As[i*2048 + wid*512]);
    }
#pragma unroll
    for (int i = 0; i < 2; ++i) {
      int row = i*32 + arow;
      gload_lds16(Bw + (size_t)(n0+row)*K + k0 + ((achk ^ (row&7)) << 3),
                  &Bs[i*2048 + wid*512]);
    }
    __syncthreads();
#pragma unroll
    for (int kh = 0; kh < 2; ++kh) {
      bf16x8 af[4], bf[2];
#pragma unroll
      for (int mf = 0; mf < 4; ++mf) {
        int row = wr*64 + mf*16 + l15;
        int ch = (kh*4 + l4) ^ (row & 7);
        af[mf] = *(const bf16x8*)&As[row*64 + ch*8];
      }
#pragma unroll
      for (int nf = 0; nf < 2; ++nf) {
        int row = wc*32 + nf*16 + l15;
        int ch = (kh*4 + l4) ^ (row & 7);
        bf[nf] = *(const bf16x8*)&Bs[row*64 + ch*8];
      }
#pragma unroll
      for (int mf = 0; mf < 4; ++mf)
#pragma unroll
        for (int nf = 0; nf < 2; ++nf)
          acc[mf][nf] = __builtin_amdgcn_mfma_f32_16x16x32_bf16(af[mf], bf[nf], acc[mf][nf], 0, 0, 0);
    }
  }
#pragma unroll
  for (int mf = 0; mf < 4; ++mf)
#pragma unroll
    for (int nf = 0; nf < 2; ++nf) {
      int row = m0 + wr*64 + mf*16 + l4*4;
      int col = n0 + wc*32 + nf*16 + l15;
      float bv = bias[col];
#pragma unroll
      for (int r = 0; r < 4; ++r) {
        float val = acc[mf][nf][r] + bv;
        if constexpr (sizeof(OUT_T) == 2) C[(size_t)(row+r)*N + col] = (OUT_T)f2bf(val);
        else                              C[(size_t)(row+r)*N + col] = val;
      }
    }
}

// ---------------- causal flash attention, DH=64, QBLK=64, KVBLK=64 ---------------------
// 4 waves x 16 q-rows. Grid (32 qtiles interleaved heavy/light, H, B) = 1024 blocks.
#define S_LEN 2048
#define DMODEL 1024

__global__ __launch_bounds__(256) void attn_fwd(
    const u16* __restrict__ Qp, const u16* __restrict__ Kp,
    const u16* __restrict__ Vp, u16* __restrict__ AO)
{
  // u16 units: [0,4096) Q staging then per-wave P (wave w: w*1024..w*1024+1024)
  // [4096,8192) K tile [64][64] swizzled; [8192,12288) V^T tile [64][64] swizzled
  __shared__ __align__(16) u16 lds[12288];
  const int t = threadIdx.x;
  const int wid = t >> 6, l = t & 63;
  const int l4 = l >> 4, l15 = l & 15;
  const int gx = blockIdx.x;
  const int qt = (gx & 1) ? (gx >> 1) : (31 - (gx >> 1));   // heavy/light interleave
  const int q0 = qt * 64;
  const int h = blockIdx.y, b = blockIdx.z;
  const size_t hoff = (size_t)b * S_LEN * DMODEL + (size_t)h * 64;
  const u16* Qg = Qp + hoff;
  const u16* Kg = Kp + hoff;
  const u16* Vg = Vp + hoff;
  const int arow = t >> 3, achk = t & 7;

  // stage Q tile [64][64] swizzled
#pragma unroll
  for (int i = 0; i < 2; ++i) {
    int row = i*32 + arow;
    gload_lds16(Qg + (size_t)(q0+row)*DMODEL + ((achk ^ (row&7)) << 3),
                &lds[i*2048 + wid*512]);
  }
  __syncthreads();
  bf16x8 qf[2];
#pragma unroll
  for (int kh = 0; kh < 2; ++kh) {
    int row = wid*16 + l15;
    int ch = (kh*4 + l4) ^ (row & 7);
    qf[kh] = *(const bf16x8*)&lds[row*64 + ch*8];
  }

  float mi[4], li[4];
  f32x4 o[4] = {};
#pragma unroll
  for (int r = 0; r < 4; ++r) { mi[r] = -INFINITY; li[r] = 0.f; }

  const int qw0 = q0 + wid*16;
  const int nt = qt + 1;

  for (int kt = 0; kt < nt; ++kt) {
    const int k0 = kt*64;
    __syncthreads();
#pragma unroll
    for (int i = 0; i < 2; ++i) {           // K tile, swizzled, via global_load_lds
      int row = i*32 + arow;
      gload_lds16(Kg + (size_t)(k0+row)*DMODEL + ((achk ^ (row&7)) << 3),
                  &lds[4096 + i*2048 + wid*512]);
    }
#pragma unroll
    for (int i = 0; i < 2; ++i) {           // V tile transposed via regs, two-level swizzle
      int vr = i*32 + arow;
      u16x8 vv = *(const u16x8*)(Vg + (size_t)(k0+vr)*DMODEL + achk*8);
#pragma unroll
      for (int j = 0; j < 8; ++j) {
        int d = achk*8 + j;
        int ch = (vr >> 3) ^ (d & 7) ^ ((d >> 3) & 7);
        lds[8192 + d*64 + ch*8 + (vr & 7)] = vv[j];
      }
    }
    __syncthreads();

    if (k0 <= qw0 + 15) {
      f32x4 s[4] = {};
#pragma unroll
      for (int kh = 0; kh < 2; ++kh) {
        bf16x8 kf[4];
#pragma unroll
        for (int nf = 0; nf < 4; ++nf) {
          int row = nf*16 + l15;
          int ch = (kh*4 + l4) ^ (row & 7);
          kf[nf] = *(const bf16x8*)&lds[4096 + row*64 + ch*8];
        }
#pragma unroll
        for (int nf = 0; nf < 4; ++nf)
          s[nf] = __builtin_amdgcn_mfma_f32_16x16x32_bf16(qf[kh], kf[nf], s[nf], 0,0,0);
      }
      const bool needmask = (k0 + 63) > qw0;
      float corr[4];
#pragma unroll
      for (int r = 0; r < 4; ++r) {
        float mx = -INFINITY;
#pragma unroll
        for (int nf = 0; nf < 4; ++nf) {
          float vsc = s[nf][r] * 0.125f;
          if (needmask) {
            int qq = qw0 + l4*4 + r;
            int kk2 = k0 + nf*16 + l15;
            if (kk2 > qq) vsc = -INFINITY;
          }
          s[nf][r] = vsc;
          mx = fmaxf(mx, vsc);
        }
        mx = fmaxf(mx, __shfl_xor(mx, 1, 64));
        mx = fmaxf(mx, __shfl_xor(mx, 2, 64));
        mx = fmaxf(mx, __shfl_xor(mx, 4, 64));
        mx = fmaxf(mx, __shfl_xor(mx, 8, 64));
        float mn = fmaxf(mi[r], mx);
        corr[r] = __expf(mi[r] - mn);
        float sum = 0.f;
#pragma unroll
        for (int nf = 0; nf < 4; ++nf) {
          float p = __expf(s[nf][r] - mn);
          s[nf][r] = p;
          sum += p;
        }
        sum += __shfl_xor(sum, 1, 64);
        sum += __shfl_xor(sum, 2, 64);
        sum += __shfl_xor(sum, 4, 64);
        sum += __shfl_xor(sum, 8, 64);
        li[r] = li[r]*corr[r] + sum;
        mi[r] = mn;
      }
#pragma unroll
      for (int df = 0; df < 4; ++df)
#pragma unroll
        for (int r = 0; r < 4; ++r) o[df][r] *= corr[r];
      // P -> LDS (wave-private, reuses Q region), swizzled
      const int pbase = wid*1024;
#pragma unroll
      for (int nf = 0; nf < 4; ++nf)
#pragma unroll
        for (int r = 0; r < 4; ++r) {
          int prow = l4*4 + r;
          int pcol = nf*16 + l15;
          lds[pbase + prow*64 + (((pcol>>3) ^ (prow&7))<<3) + (pcol&7)] = f2bf(s[nf][r]);
        }
      asm volatile("s_waitcnt lgkmcnt(0)" ::: "memory");
      // PV
#pragma unroll
      for (int kh = 0; kh < 2; ++kh) {
        bf16x8 pf, vf[4];
        {
          int prow = l15;
          int ch = (kh*4 + l4) ^ (prow & 7);
          pf = *(const bf16x8*)&lds[pbase + prow*64 + ch*8];
        }
#pragma unroll
        for (int df = 0; df < 4; ++df) {
          int d = df*16 + l15;
          int ch = (kh*4 + l4) ^ (d & 7) ^ ((d >> 3) & 7);
          vf[df] = *(const bf16x8*)&lds[8192 + d*64 + ch*8];
        }
#pragma unroll
        for (int df = 0; df < 4; ++df)
          o[df] = __builtin_amdgcn_mfma_f32_16x16x32_bf16(pf, vf[df], o[df], 0,0,0);
      }
    }
  }
#pragma unroll
  for (int df = 0; df < 4; ++df) {
    int row = qw0 + l4*4;
    int col = h*64 + df*16 + l15;
#pragma unroll
    for (int r = 0; r < 4; ++r) {
      float val = o[df][r] / li[r];
      AO[((size_t)b*S_LEN + row + r)*DMODEL + col] = f2bf(val);
    }
  }
}

// ---------------------------------------------------------------------------------------
extern "C" void kernel_launch(void* const* d_in, const int* in_sizes, int n_in,
                              void* d_out, int out_size, void* d_ws, size_t ws_size,
                              hipStream_t stream)
{
  const float* q  = (const float*)d_in[0];
  const float* k  = (const float*)d_in[1];
  const float* v  = (const float*)d_in[2];
  // d_in[3] = mask (causal tril; applied analytically)
  const float* Wq = (const float*)d_in[4];
  const float* bq = (const float*)d_in[5];
  const float* Wk = (const float*)d_in[6];
  const float* bk = (const float*)d_in[7];
  const float* Wv = (const float*)d_in[8];
  const float* bv = (const float*)d_in[9];
  const float* Wo = (const float*)d_in[10];
  const float* bo = (const float*)d_in[11];
  float* out = (float*)d_out;

  u16* ws  = (u16*)d_ws;
  u16* qb  = ws;                 // [4096,1024] bf16
  u16* Wqb = ws + 12582912;
  u16* Wkb = ws + 13631488;
  u16* Wvb = ws + 14680064;
  u16* Wob = ws + 15728640;
  u16* kb  = ws + 4194304;
  u16* vb  = ws + 8388608;
  u16* Qp  = ws + 16777216;
  u16* Kp  = ws + 20971520;
  u16* Vp  = ws + 25165824;
  u16* AO  = ws + 29360128;      // total 33554432 u16 = 64 MB

  convert_all<<<8192, 256, 0, stream>>>(q, k, v, Wq, Wk, Wv, Wo, qb);

  dim3 g1(16, 32);
  gemm_nt<u16><<<g1, 256, 0, stream>>>(qb, Wqb, bq, Qp, 4096, 1024, 1024);
  gemm_nt<u16><<<g1, 256, 0, stream>>>(kb, Wkb, bk, Kp, 4096, 1024, 1024);
  gemm_nt<u16><<<g1, 256, 0, stream>>>(vb, Wvb, bv, Vp, 4096, 1024, 1024);

  dim3 ga(32, 16, 2);
  attn_fwd<<<ga, 256, 0, stream>>>(Qp, Kp, Vp, AO);

  gemm_nt<float><<<g1, 256, 0, stream>>>(AO, Wob, bo, out, 4096, 1024, 1024);
}

// Round 3
// 198.365 us; speedup vs baseline: 1.1510x; 1.1510x over previous
//
#include <hip/hip_runtime.h>

typedef unsigned int u32;
typedef unsigned short u16;
typedef __attribute__((ext_vector_type(8))) short bf16x8;
typedef __attribute__((ext_vector_type(8))) u16 u16x8;
typedef __attribute__((ext_vector_type(4))) float f32x4;

#define AS1 __attribute__((address_space(1)))
#define AS3 __attribute__((address_space(3)))

__device__ __forceinline__ void gload_lds16(const void* g, void* l) {
  __builtin_amdgcn_global_load_lds((const AS1 u32*)g, (AS3 u32*)l, 16, 0, 0);
}

__device__ __forceinline__ u16 f2bf(float f) {
  union { float f; u32 u; } x; x.f = f;
  u32 u = x.u;
  return (u16)((u + 0x7fffu + ((u >> 16) & 1u)) >> 16);
}

// ---------------- convert fp32 -> bf16 (q,k,v,Wq,Wk,Wv,Wo packed contiguously) ---------
__global__ __launch_bounds__(256) void convert_all(
    const float* __restrict__ q, const float* __restrict__ k, const float* __restrict__ v,
    const float* __restrict__ wq, const float* __restrict__ wk,
    const float* __restrict__ wv, const float* __restrict__ wo,
    u16* __restrict__ dst)
{
  int b = blockIdx.x, t = threadIdx.x;
  const float* sp; size_t lb;
  if (b < 6144) {
    sp = (b < 2048) ? q : ((b < 4096) ? k : v);
    lb = (size_t)(b & 2047) * 2048;
  } else {
    int w = (b - 6144) >> 9;
    sp = (w == 0) ? wq : ((w == 1) ? wk : ((w == 2) ? wv : wo));
    lb = (size_t)((b - 6144) & 511) * 2048;
  }
  lb += (size_t)t * 8;
  f32x4 f0 = *(const f32x4*)(sp + lb);
  f32x4 f1 = *(const f32x4*)(sp + lb + 4);
  u16x8 o;
  o[0]=f2bf(f0[0]); o[1]=f2bf(f0[1]); o[2]=f2bf(f0[2]); o[3]=f2bf(f0[3]);
  o[4]=f2bf(f1[0]); o[5]=f2bf(f1[1]); o[6]=f2bf(f1[2]); o[7]=f2bf(f1[3]);
  *(u16x8*)(dst + (size_t)b*2048 + (size_t)t*8) = o;
}

// ---------------- GEMM: C[M,N] = A[M,K] * B[N,K]^T + bias, bf16 in, OUT_T out ----------
// BM=128 BN=64 BK=64, 256 threads (4 waves, 2x2), wave tile 64x32.
template<typename OUT_T>
__global__ __launch_bounds__(256) void gemm_nt(
    const u16* __restrict__ A, const u16* __restrict__ Bw,
    const float* __restrict__ bias, OUT_T* __restrict__ C,
    int M, int N, int K)
{
  __shared__ __align__(16) u16 As[128*64];
  __shared__ __align__(16) u16 Bs[64*64];
  const int t = threadIdx.x;
  const int wid = t >> 6, l = t & 63;
  const int l4 = l >> 4, l15 = l & 15;
  const int m0 = blockIdx.y * 128, n0 = blockIdx.x * 64;
  const int wr = wid >> 1, wc = wid & 1;
  const int arow = t >> 3, achk = t & 7;

  f32x4 acc[4][2] = {};

  for (int k0 = 0; k0 < K; k0 += 64) {
    __syncthreads();
#pragma unroll
    for (int i = 0; i < 4; ++i) {
      int row = i*32 + arow;
      gload_lds16(A + (size_t)(m0+row)*K + k0 + ((achk ^ (row&7)) << 3),
                  &As[i*2048 + wid*512]);
    }
#pragma unroll
    for (int i = 0; i < 2; ++i) {
      int row = i*32 + arow;
      gload_lds16(Bw + (size_t)(n0+row)*K + k0 + ((achk ^ (row&7)) << 3),
                  &Bs[i*2048 + wid*512]);
    }
    __syncthreads();
#pragma unroll
    for (int kh = 0; kh < 2; ++kh) {
      bf16x8 af[4], bf[2];
#pragma unroll
      for (int mf = 0; mf < 4; ++mf) {
        int row = wr*64 + mf*16 + l15;
        int ch = (kh*4 + l4) ^ (row & 7);
        af[mf] = *(const bf16x8*)&As[row*64 + ch*8];
      }
#pragma unroll
      for (int nf = 0; nf < 2; ++nf) {
        int row = wc*32 + nf*16 + l15;
        int ch = (kh*4 + l4) ^ (row & 7);
        bf[nf] = *(const bf16x8*)&Bs[row*64 + ch*8];
      }
#pragma unroll
      for (int mf = 0; mf < 4; ++mf)
#pragma unroll
        for (int nf = 0; nf < 2; ++nf)
          acc[mf][nf] = __builtin_amdgcn_mfma_f32_16x16x32_bf16(af[mf], bf[nf], acc[mf][nf], 0, 0, 0);
    }
  }
#pragma unroll
  for (int mf = 0; mf < 4; ++mf)
#pragma unroll
    for (int nf = 0; nf < 2; ++nf) {
      int row = m0 + wr*64 + mf*16 + l4*4;
      int col = n0 + wc*32 + nf*16 + l15;
      float bv = bias[col];
#pragma unroll
      for (int r = 0; r < 4; ++r) {
        float val = acc[mf][nf][r] + bv;
        if constexpr (sizeof(OUT_T) == 2) C[(size_t)(row+r)*N + col] = (OUT_T)f2bf(val);
        else                              C[(size_t)(row+r)*N + col] = val;
      }
    }
}

// ---------------- causal flash attention, DH=64, QBLK=64, KVBLK=64 ---------------------
// 4 waves x 16 q-rows. Grid (32, 16, 2); qt = (h&8) ? 31-gx : gx so each CU gets a
// balanced {qt, 31-qt} mix. K/V double-buffered: prefetch issued before compute, single
// barrier per iteration (its implicit vmcnt(0) drain lands after compute).
#define S_LEN 2048
#define DMODEL 1024

__global__ __launch_bounds__(256) void attn_fwd(
    const u16* __restrict__ Qp, const u16* __restrict__ Kp,
    const u16* __restrict__ Vp, u16* __restrict__ AO)
{
  // u16 units: [0,4096) Q staging then per-wave P (wave w: w*1024..+1024)
  // [4096,12288) K dbuf; [12288,20480) V^T dbuf. 40 KB total -> 4 blocks/CU.
  __shared__ __align__(16) u16 lds[20480];
  const int t = threadIdx.x;
  const int wid = t >> 6, l = t & 63;
  const int l4 = l >> 4, l15 = l & 15;
  const int gx = blockIdx.x;
  const int h = blockIdx.y, b = blockIdx.z;
  const int qt = (h & 8) ? (31 - gx) : gx;
  const int q0 = qt * 64;
  const int nt = qt + 1;
  const size_t hoff = (size_t)b * S_LEN * DMODEL + (size_t)h * 64;
  const u16* Qg = Qp + hoff;
  const u16* Kg = Kp + hoff;
  const u16* Vg = Vp + hoff;
  const int arow = t >> 3, achk = t & 7;
  const float SC = 0.18033688f;  // 0.125 * log2(e)

  // prologue: stage Q + K0 via global_load_lds; V0 -> regs
#pragma unroll
  for (int i = 0; i < 2; ++i) {
    int row = i*32 + arow;
    gload_lds16(Qg + (size_t)(q0+row)*DMODEL + ((achk ^ (row&7)) << 3),
                &lds[i*2048 + wid*512]);
  }
#pragma unroll
  for (int i = 0; i < 2; ++i) {
    int row = i*32 + arow;
    gload_lds16(Kg + (size_t)row*DMODEL + ((achk ^ (row&7)) << 3),
                &lds[4096 + i*2048 + wid*512]);
  }
  u16x8 vv0 = *(const u16x8*)(Vg + (size_t)arow*DMODEL + achk*8);
  u16x8 vv1 = *(const u16x8*)(Vg + (size_t)(32+arow)*DMODEL + achk*8);
  __syncthreads();               // Q, K0 staged; V0 in regs

  bf16x8 qf[2];
#pragma unroll
  for (int kh = 0; kh < 2; ++kh) {
    int row = wid*16 + l15;
    int ch = (kh*4 + l4) ^ (row & 7);
    qf[kh] = *(const bf16x8*)&lds[row*64 + ch*8];
  }
  // write V0 -> Vbuf0 (swizzled transpose)
#pragma unroll
  for (int ii = 0; ii < 2; ++ii) {
    int vr = ii*32 + arow;
    const u16x8& vv = ii ? vv1 : vv0;
#pragma unroll
    for (int j = 0; j < 8; ++j) {
      int d = achk*8 + j;
      int ch = (vr >> 3) ^ (d & 7) ^ ((d >> 3) & 7);
      lds[12288 + d*64 + ch*8 + (vr & 7)] = vv[j];
    }
  }
  __syncthreads();               // V0 visible; Q frags read

  float mi[4], li[4];
  f32x4 o[4] = {};
#pragma unroll
  for (int r = 0; r < 4; ++r) { mi[r] = -INFINITY; li[r] = 0.f; }
  const int qw0 = q0 + wid*16;

  for (int i = 0; i < nt; ++i) {
    const int cur = i & 1, nxt = cur ^ 1;
    const int k0 = i*64;
    const u16* Kb = &lds[4096 + cur*4096];
    const u16* Vb = &lds[12288 + cur*4096];
    const bool pf = (i + 1 < nt);

    if (pf) {                    // prefetch next K->LDS (async), V->regs
      const int k0n = k0 + 64;
#pragma unroll
      for (int ii = 0; ii < 2; ++ii) {
        int row = ii*32 + arow;
        gload_lds16(Kg + (size_t)(k0n+row)*DMODEL + ((achk ^ (row&7)) << 3),
                    &lds[4096 + nxt*4096 + ii*2048 + wid*512]);
      }
      vv0 = *(const u16x8*)(Vg + (size_t)(k0n+arow)*DMODEL + achk*8);
      vv1 = *(const u16x8*)(Vg + (size_t)(k0n+32+arow)*DMODEL + achk*8);
    }

    // QK^T
    f32x4 s[4] = {};
#pragma unroll
    for (int kh = 0; kh < 2; ++kh) {
      bf16x8 kf[4];
#pragma unroll
      for (int nf = 0; nf < 4; ++nf) {
        int row = nf*16 + l15;
        int ch = (kh*4 + l4) ^ (row & 7);
        kf[nf] = *(const bf16x8*)&Kb[row*64 + ch*8];
      }
#pragma unroll
      for (int nf = 0; nf < 4; ++nf)
        s[nf] = __builtin_amdgcn_mfma_f32_16x16x32_bf16(qf[kh], kf[nf], s[nf], 0,0,0);
    }

    // online softmax (base-2)
    const bool needmask = (i == qt);
    float corr[4];
#pragma unroll
    for (int r = 0; r < 4; ++r) {
      float mx = -INFINITY;
#pragma unroll
      for (int nf = 0; nf < 4; ++nf) {
        float vsc = s[nf][r] * SC;
        if (needmask) {
          int qq = qw0 + l4*4 + r;
          int kk2 = k0 + nf*16 + l15;
          if (kk2 > qq) vsc = -INFINITY;
        }
        s[nf][r] = vsc;
        mx = fmaxf(mx, vsc);
      }
      mx = fmaxf(mx, __shfl_xor(mx, 1, 64));
      mx = fmaxf(mx, __shfl_xor(mx, 2, 64));
      mx = fmaxf(mx, __shfl_xor(mx, 4, 64));
      mx = fmaxf(mx, __shfl_xor(mx, 8, 64));
      float mn = fmaxf(mi[r], mx);
      corr[r] = exp2f(mi[r] - mn);
      float sum = 0.f;
#pragma unroll
      for (int nf = 0; nf < 4; ++nf) {
        float p = exp2f(s[nf][r] - mn);
        s[nf][r] = p;
        sum += p;
      }
      sum += __shfl_xor(sum, 1, 64);
      sum += __shfl_xor(sum, 2, 64);
      sum += __shfl_xor(sum, 4, 64);
      sum += __shfl_xor(sum, 8, 64);
      li[r] = li[r]*corr[r] + sum;
      mi[r] = mn;
    }
#pragma unroll
    for (int df = 0; df < 4; ++df)
#pragma unroll
      for (int r = 0; r < 4; ++r) o[df][r] *= corr[r];

    // P -> LDS (wave-private, reuses Q region), swizzled
    const int pbase = wid*1024;
#pragma unroll
    for (int nf = 0; nf < 4; ++nf)
#pragma unroll
      for (int r = 0; r < 4; ++r) {
        int prow = l4*4 + r;
        int pcol = nf*16 + l15;
        lds[pbase + prow*64 + (((pcol>>3) ^ (prow&7))<<3) + (pcol&7)] = f2bf(s[nf][r]);
      }
    asm volatile("s_waitcnt lgkmcnt(0)" ::: "memory");

    // PV
#pragma unroll
    for (int kh = 0; kh < 2; ++kh) {
      bf16x8 pfr, vf[4];
      {
        int prow = l15;
        int ch = (kh*4 + l4) ^ (prow & 7);
        pfr = *(const bf16x8*)&lds[pbase + prow*64 + ch*8];
      }
#pragma unroll
      for (int df = 0; df < 4; ++df) {
        int d = df*16 + l15;
        int ch = (kh*4 + l4) ^ (d & 7) ^ ((d >> 3) & 7);
        vf[df] = *(const bf16x8*)&Vb[d*64 + ch*8];
      }
#pragma unroll
      for (int df = 0; df < 4; ++df)
        o[df] = __builtin_amdgcn_mfma_f32_16x16x32_bf16(pfr, vf[df], o[df], 0,0,0);
    }

    // write-late: V(i+1) regs -> Vbuf[nxt] (compiler inserts vmcnt wait on vv here)
    if (pf) {
#pragma unroll
      for (int ii = 0; ii < 2; ++ii) {
        int vr = ii*32 + arow;
        const u16x8& vv = ii ? vv1 : vv0;
#pragma unroll
        for (int j = 0; j < 8; ++j) {
          int d = achk*8 + j;
          int ch = (vr >> 3) ^ (d & 7) ^ ((d >> 3) & 7);
          lds[12288 + nxt*4096 + d*64 + ch*8 + (vr & 7)] = vv[j];
        }
      }
    }
    __syncthreads();             // drains vmcnt(0) (K prefetch) + publishes V writes
  }

#pragma unroll
  for (int df = 0; df < 4; ++df) {
    int row = qw0 + l4*4;
    int col = h*64 + df*16 + l15;
#pragma unroll
    for (int r = 0; r < 4; ++r) {
      float val = o[df][r] / li[r];
      AO[((size_t)b*S_LEN + row + r)*DMODEL + col] = f2bf(val);
    }
  }
}

// ---------------------------------------------------------------------------------------
extern "C" void kernel_launch(void* const* d_in, const int* in_sizes, int n_in,
                              void* d_out, int out_size, void* d_ws, size_t ws_size,
                              hipStream_t stream)
{
  const float* q  = (const float*)d_in[0];
  const float* k  = (const float*)d_in[1];
  const float* v  = (const float*)d_in[2];
  // d_in[3] = mask (causal tril; applied analytically)
  const float* Wq = (const float*)d_in[4];
  const float* bq = (const float*)d_in[5];
  const float* Wk = (const float*)d_in[6];
  const float* bk = (const float*)d_in[7];
  const float* Wv = (const float*)d_in[8];
  const float* bv = (const float*)d_in[9];
  const float* Wo = (const float*)d_in[10];
  const float* bo = (const float*)d_in[11];
  float* out = (float*)d_out;

  u16* ws  = (u16*)d_ws;
  u16* qb  = ws;                 // [4096,1024] bf16
  u16* Wqb = ws + 12582912;
  u16* Wkb = ws + 13631488;
  u16* Wvb = ws + 14680064;
  u16* Wob = ws + 15728640;
  u16* kb  = ws + 4194304;
  u16* vb  = ws + 8388608;
  u16* Qp  = ws + 16777216;
  u16* Kp  = ws + 20971520;
  u16* Vp  = ws + 25165824;
  u16* AO  = ws + 29360128;      // total 33554432 u16 = 64 MB

  convert_all<<<8192, 256, 0, stream>>>(q, k, v, Wq, Wk, Wv, Wo, qb);

  dim3 g1(16, 32);
  gemm_nt<u16><<<g1, 256, 0, stream>>>(qb, Wqb, bq, Qp, 4096, 1024, 1024);
  gemm_nt<u16><<<g1, 256, 0, stream>>>(kb, Wkb, bk, Kp, 4096, 1024, 1024);
  gemm_nt<u16><<<g1, 256, 0, stream>>>(vb, Wvb, bv, Vp, 4096, 1024, 1024);

  dim3 ga(32, 16, 2);
  attn_fwd<<<ga, 256, 0, stream>>>(Qp, Kp, Vp, AO);

  gemm_nt<float><<<g1, 256, 0, stream>>>(AO, Wob, bo, out, 4096, 1024, 1024);
}

// Round 4
// 136.453 us; speedup vs baseline: 1.6732x; 1.4537x over previous
//
#include <hip/hip_runtime.h>

typedef unsigned int u32;
typedef unsigned short u16;
typedef __attribute__((ext_vector_type(8))) short bf16x8;
typedef __attribute__((ext_vector_type(8))) u16 u16x8;
typedef __attribute__((ext_vector_type(4))) float f32x4;
typedef __attribute__((ext_vector_type(2))) u32 u32x2;

#define AS1 __attribute__((address_space(1)))
#define AS3 __attribute__((address_space(3)))

__device__ __forceinline__ void gload_lds16(const void* g, void* l) {
  __builtin_amdgcn_global_load_lds((const AS1 u32*)g, (AS3 u32*)l, 16, 0, 0);
}

__device__ __forceinline__ u16 f2bf(float f) {
  union { float f; u32 u; } x; x.f = f;
  u32 u = x.u;
  return (u16)((u + 0x7fffu + ((u >> 16) & 1u)) >> 16);
}

__device__ __forceinline__ u32 cvt_pk_bf16(float lo, float hi) {
  u32 r;
  asm("v_cvt_pk_bf16_f32 %0, %1, %2" : "=v"(r) : "v"(lo), "v"(hi));
  return r;
}

// ---------------- convert fp32 -> bf16 (q,k,v,Wq,Wk,Wv,Wo packed contiguously) ---------
__global__ __launch_bounds__(256) void convert_all(
    const float* __restrict__ q, const float* __restrict__ k, const float* __restrict__ v,
    const float* __restrict__ wq, const float* __restrict__ wk,
    const float* __restrict__ wv, const float* __restrict__ wo,
    u16* __restrict__ dst)
{
  int b = blockIdx.x, t = threadIdx.x;
  const float* sp; size_t lb;
  if (b < 6144) {
    sp = (b < 2048) ? q : ((b < 4096) ? k : v);
    lb = (size_t)(b & 2047) * 2048;
  } else {
    int w = (b - 6144) >> 9;
    sp = (w == 0) ? wq : ((w == 1) ? wk : ((w == 2) ? wv : wo));
    lb = (size_t)((b - 6144) & 511) * 2048;
  }
  lb += (size_t)t * 8;
  f32x4 f0 = *(const f32x4*)(sp + lb);
  f32x4 f1 = *(const f32x4*)(sp + lb + 4);
  u16x8 o;
  o[0]=f2bf(f0[0]); o[1]=f2bf(f0[1]); o[2]=f2bf(f0[2]); o[3]=f2bf(f0[3]);
  o[4]=f2bf(f1[0]); o[5]=f2bf(f1[1]); o[6]=f2bf(f1[2]); o[7]=f2bf(f1[3]);
  *(u16x8*)(dst + (size_t)b*2048 + (size_t)t*8) = o;
}

// ---------------- fused QKV GEMM: C[4096,3072], col block picks (input, weight, bias) --
__global__ __launch_bounds__(256) void gemm_qkv(
    const u16* __restrict__ Xall,   // [3][4096][1024] bf16 (q,k,v)
    const u16* __restrict__ Wall,   // [3][1024][1024] bf16 (Wq,Wk,Wv)
    const float* __restrict__ bq, const float* __restrict__ bk, const float* __restrict__ bv,
    u16* __restrict__ C)            // [4096][3072]
{
  __shared__ __align__(16) u16 As[128*64];
  __shared__ __align__(16) u16 Bs[64*64];
  const int t = threadIdx.x;
  const int wid = t >> 6, l = t & 63;
  const int l4 = l >> 4, l15 = l & 15;
  const int n0g = blockIdx.x * 64;
  const int which = n0g >> 10;
  const int n0 = n0g & 1023;
  const u16* A  = Xall + (size_t)which * 4194304;
  const u16* Bw = Wall + (size_t)which * 1048576;
  const float* bias = (which == 0) ? bq : ((which == 1) ? bk : bv);
  const int m0 = blockIdx.y * 128;
  const int wr = wid >> 1, wc = wid & 1;
  const int arow = t >> 3, achk = t & 7;

  f32x4 acc[4][2] = {};

  for (int k0 = 0; k0 < 1024; k0 += 64) {
    __syncthreads();
#pragma unroll
    for (int i = 0; i < 4; ++i) {
      int row = i*32 + arow;
      gload_lds16(A + (size_t)(m0+row)*1024 + k0 + ((achk ^ (row&7)) << 3),
                  &As[i*2048 + wid*512]);
    }
#pragma unroll
    for (int i = 0; i < 2; ++i) {
      int row = i*32 + arow;
      gload_lds16(Bw + (size_t)(n0+row)*1024 + k0 + ((achk ^ (row&7)) << 3),
                  &Bs[i*2048 + wid*512]);
    }
    __syncthreads();
#pragma unroll
    for (int kh = 0; kh < 2; ++kh) {
      bf16x8 af[4], bf[2];
#pragma unroll
      for (int mf = 0; mf < 4; ++mf) {
        int row = wr*64 + mf*16 + l15;
        int ch = (kh*4 + l4) ^ (row & 7);
        af[mf] = *(const bf16x8*)&As[row*64 + ch*8];
      }
#pragma unroll
      for (int nf = 0; nf < 2; ++nf) {
        int row = wc*32 + nf*16 + l15;
        int ch = (kh*4 + l4) ^ (row & 7);
        bf[nf] = *(const bf16x8*)&Bs[row*64 + ch*8];
      }
#pragma unroll
      for (int mf = 0; mf < 4; ++mf)
#pragma unroll
        for (int nf = 0; nf < 2; ++nf)
          acc[mf][nf] = __builtin_amdgcn_mfma_f32_16x16x32_bf16(af[mf], bf[nf], acc[mf][nf], 0, 0, 0);
    }
  }
#pragma unroll
  for (int mf = 0; mf < 4; ++mf)
#pragma unroll
    for (int nf = 0; nf < 2; ++nf) {
      int row = m0 + wr*64 + mf*16 + l4*4;
      int colg = n0g + wc*32 + nf*16 + l15;
      float bv = bias[n0 + wc*32 + nf*16 + l15];
#pragma unroll
      for (int r = 0; r < 4; ++r)
        C[(size_t)(row+r)*3072 + colg] = f2bf(acc[mf][nf][r] + bv);
    }
}

// ---------------- GEMM: C[M,N] = A[M,K] * B[N,K]^T + bias, bf16 in, fp32 out -----------
__global__ __launch_bounds__(256) void gemm_out(
    const u16* __restrict__ A, const u16* __restrict__ Bw,
    const float* __restrict__ bias, float* __restrict__ C)
{
  __shared__ __align__(16) u16 As[128*64];
  __shared__ __align__(16) u16 Bs[64*64];
  const int t = threadIdx.x;
  const int wid = t >> 6, l = t & 63;
  const int l4 = l >> 4, l15 = l & 15;
  const int m0 = blockIdx.y * 128, n0 = blockIdx.x * 64;
  const int wr = wid >> 1, wc = wid & 1;
  const int arow = t >> 3, achk = t & 7;

  f32x4 acc[4][2] = {};

  for (int k0 = 0; k0 < 1024; k0 += 64) {
    __syncthreads();
#pragma unroll
    for (int i = 0; i < 4; ++i) {
      int row = i*32 + arow;
      gload_lds16(A + (size_t)(m0+row)*1024 + k0 + ((achk ^ (row&7)) << 3),
                  &As[i*2048 + wid*512]);
    }
#pragma unroll
    for (int i = 0; i < 2; ++i) {
      int row = i*32 + arow;
      gload_lds16(Bw + (size_t)(n0+row)*1024 + k0 + ((achk ^ (row&7)) << 3),
                  &Bs[i*2048 + wid*512]);
    }
    __syncthreads();
#pragma unroll
    for (int kh = 0; kh < 2; ++kh) {
      bf16x8 af[4], bf[2];
#pragma unroll
      for (int mf = 0; mf < 4; ++mf) {
        int row = wr*64 + mf*16 + l15;
        int ch = (kh*4 + l4) ^ (row & 7);
        af[mf] = *(const bf16x8*)&As[row*64 + ch*8];
      }
#pragma unroll
      for (int nf = 0; nf < 2; ++nf) {
        int row = wc*32 + nf*16 + l15;
        int ch = (kh*4 + l4) ^ (row & 7);
        bf[nf] = *(const bf16x8*)&Bs[row*64 + ch*8];
      }
#pragma unroll
      for (int mf = 0; mf < 4; ++mf)
#pragma unroll
        for (int nf = 0; nf < 2; ++nf)
          acc[mf][nf] = __builtin_amdgcn_mfma_f32_16x16x32_bf16(af[mf], bf[nf], acc[mf][nf], 0, 0, 0);
    }
  }
#pragma unroll
  for (int mf = 0; mf < 4; ++mf)
#pragma unroll
    for (int nf = 0; nf < 2; ++nf) {
      int row = m0 + wr*64 + mf*16 + l4*4;
      int col = n0 + wc*32 + nf*16 + l15;
      float bv = bias[col];
#pragma unroll
      for (int r = 0; r < 4; ++r)
        C[(size_t)(row+r)*1024 + col] = acc[mf][nf][r] + bv;
    }
}

// ---------------- causal flash attention, DH=64, QBLK=64, KVBLK=64 ---------------------
// Block p handles q-tile pair {p, 31-p}: exactly 33 KV-iterations per block -> uniform
// work under ANY block->CU mapping. Swapped QK^T (mfma(K,Q)) => lane owns one q-row:
// softmax = in-register reduce + 2 shuffles. Grid (16,16,2) = 512 blocks.
#define QSTRIDE 3072

__global__ __launch_bounds__(256) void attn_fwd(
    const u16* __restrict__ QKV, u16* __restrict__ AO)
{
  // u16 units: [0,4096) Q staging / per-wave P (wave w: w*1024..+1024)
  // [4096,12288) K dbuf; [12288,20480) V^T dbuf. 40 KB.
  __shared__ __align__(16) u16 lds[20480];
  const int t = threadIdx.x;
  const int wid = t >> 6, l = t & 63;
  const int g = l >> 4, c = l & 15;
  const int h = blockIdx.y, b = blockIdx.z;
  const size_t base = (size_t)b * 2048 * QSTRIDE + (size_t)h * 64;
  const u16* Qg = QKV + base;
  const u16* Kg = QKV + base + 1024;
  const u16* Vg = QKV + base + 2048;
  const int arow = t >> 3, achk = t & 7;
  const float SC = 0.18033688f;  // (1/8) * log2(e)
  const int pbase = wid * 1024;
  const int cs = (c & 7) ^ ((c >> 3) << 2);   // P-region swizzle component

  for (int half = 0; half < 2; ++half) {
    const int qt = half ? (31 - (int)blockIdx.x) : (int)blockIdx.x;
    const int q0 = qt * 64;
    const int qw0 = q0 + wid * 16;

    // ---- prologue: stage Q + K0 (async LDS), V0 -> regs
#pragma unroll
    for (int i = 0; i < 2; ++i) {
      int row = i*32 + arow;
      gload_lds16(Qg + (size_t)(q0+row)*QSTRIDE + ((achk ^ (row&7)) << 3),
                  &lds[i*2048 + wid*512]);
    }
#pragma unroll
    for (int i = 0; i < 2; ++i) {
      int row = i*32 + arow;
      gload_lds16(Kg + (size_t)row*QSTRIDE + ((achk ^ (row&7)) << 3),
                  &lds[4096 + i*2048 + wid*512]);
    }
    u16x8 vv0 = *(const u16x8*)(Vg + (size_t)arow*QSTRIDE + achk*8);
    u16x8 vv1 = *(const u16x8*)(Vg + (size_t)(32+arow)*QSTRIDE + achk*8);
    __syncthreads();

    bf16x8 qf[2];
#pragma unroll
    for (int kh = 0; kh < 2; ++kh) {
      int row = wid*16 + c;
      int ch = (kh*4 + g) ^ (row & 7);
      qf[kh] = *(const bf16x8*)&lds[row*64 + ch*8];
    }
#pragma unroll
    for (int ii = 0; ii < 2; ++ii) {
      int vr = ii*32 + arow;
      const u16x8& vv = ii ? vv1 : vv0;
#pragma unroll
      for (int j = 0; j < 8; ++j) {
        int d = achk*8 + j;
        int ch = (vr >> 3) ^ (d & 7) ^ ((d >> 3) & 7);
        lds[12288 + d*64 + ch*8 + (vr & 7)] = vv[j];
      }
    }
    __syncthreads();

    float mi = -INFINITY, li = 0.f;
    f32x4 o[4] = {};

    for (int i = 0; i <= qt; ++i) {
      const int cur = i & 1, nxt = cur ^ 1;
      const u16* Kb = &lds[4096 + cur*4096];
      const u16* Vb = &lds[12288 + cur*4096];
      const bool pfch = (i < qt);

      if (pfch) {                 // prefetch next K->LDS (async), V->regs
        const int k0n = (i+1)*64;
#pragma unroll
        for (int ii = 0; ii < 2; ++ii) {
          int row = ii*32 + arow;
          gload_lds16(Kg + (size_t)(k0n+row)*QSTRIDE + ((achk ^ (row&7)) << 3),
                      &lds[4096 + nxt*4096 + ii*2048 + wid*512]);
        }
        vv0 = *(const u16x8*)(Vg + (size_t)(k0n+arow)*QSTRIDE + achk*8);
        vv1 = *(const u16x8*)(Vg + (size_t)(k0n+32+arow)*QSTRIDE + achk*8);
      }

      // QK^T swapped: sT[nf] = K_tile x Q_tile^T -> lane holds q = c, k = 16nf+4g+r
      f32x4 sT[4] = {};
#pragma unroll
      for (int kh = 0; kh < 2; ++kh) {
        bf16x8 kf[4];
#pragma unroll
        for (int nf = 0; nf < 4; ++nf) {
          int row = nf*16 + c;
          int ch = (kh*4 + g) ^ (c & 7);
          kf[nf] = *(const bf16x8*)&Kb[row*64 + ch*8];
        }
#pragma unroll
        for (int nf = 0; nf < 4; ++nf)
          sT[nf] = __builtin_amdgcn_mfma_f32_16x16x32_bf16(kf[nf], qf[kh], sT[nf], 0,0,0);
      }

      if (i == qt) {              // diagonal: causal mask (peeled out of main path)
#pragma unroll
        for (int nf = 0; nf < 4; ++nf)
#pragma unroll
          for (int r = 0; r < 4; ++r)
            if (nf*16 + g*4 + r > wid*16 + c) sT[nf][r] = -INFINITY;
      }

      // online softmax: lane-local row reduce + 2 shuffles (replica groups g=0..3)
      float mx = fmaxf(fmaxf(sT[0][0], sT[0][1]), fmaxf(sT[0][2], sT[0][3]));
#pragma unroll
      for (int nf = 1; nf < 4; ++nf)
        mx = fmaxf(mx, fmaxf(fmaxf(sT[nf][0], sT[nf][1]), fmaxf(sT[nf][2], sT[nf][3])));
      mx = fmaxf(mx, __shfl_xor(mx, 16, 64));
      mx = fmaxf(mx, __shfl_xor(mx, 32, 64));
      float mn = fmaxf(mi, mx * SC);
      float corr = exp2f(mi - mn);
      float sum = 0.f;
#pragma unroll
      for (int nf = 0; nf < 4; ++nf)
#pragma unroll
        for (int r = 0; r < 4; ++r) {
          float pv = exp2f(fmaf(sT[nf][r], SC, -mn));
          sT[nf][r] = pv;
          sum += pv;
        }
      sum += __shfl_xor(sum, 16, 64);
      sum += __shfl_xor(sum, 32, 64);
      li = li * corr + sum;
      mi = mn;

      // corr relayout s-layout(q=c) -> o-layout(q=4g+r), rescale o
      float corr0 = __shfl(corr, g*4 + 0, 64);
      float corr1 = __shfl(corr, g*4 + 1, 64);
      float corr2 = __shfl(corr, g*4 + 2, 64);
      float corr3 = __shfl(corr, g*4 + 3, 64);
#pragma unroll
      for (int df = 0; df < 4; ++df) {
        o[df][0] *= corr0; o[df][1] *= corr1;
        o[df][2] *= corr2; o[df][3] *= corr3;
      }

      // P -> LDS: packed bf16 pairs, ds_write_b64 (wave-private region)
#pragma unroll
      for (int nf = 0; nf < 4; ++nf) {
        u32x2 w;
        w[0] = cvt_pk_bf16(sT[nf][0], sT[nf][1]);
        w[1] = cvt_pk_bf16(sT[nf][2], sT[nf][3]);
        int ch = (2*nf + (g >> 1)) ^ cs;
        *(u32x2*)&lds[pbase + c*64 + ch*8 + (g & 1)*4] = w;
      }
      asm volatile("s_waitcnt lgkmcnt(0)" ::: "memory");
      __builtin_amdgcn_sched_barrier(0);

      // PV
#pragma unroll
      for (int kh = 0; kh < 2; ++kh) {
        bf16x8 pfr, vf[4];
        {
          int ch = (kh*4 + g) ^ cs;
          pfr = *(const bf16x8*)&lds[pbase + c*64 + ch*8];
        }
#pragma unroll
        for (int df = 0; df < 4; ++df) {
          int d = df*16 + c;
          int ch = (kh*4 + g) ^ (d & 7) ^ ((d >> 3) & 7);
          vf[df] = *(const bf16x8*)&Vb[d*64 + ch*8];
        }
#pragma unroll
        for (int df = 0; df < 4; ++df)
          o[df] = __builtin_amdgcn_mfma_f32_16x16x32_bf16(pfr, vf[df], o[df], 0,0,0);
      }

      // write-late: V(i+1) regs -> Vbuf[nxt]
      if (pfch) {
#pragma unroll
        for (int ii = 0; ii < 2; ++ii) {
          int vr = ii*32 + arow;
          const u16x8& vv = ii ? vv1 : vv0;
#pragma unroll
          for (int j = 0; j < 8; ++j) {
            int d = achk*8 + j;
            int ch = (vr >> 3) ^ (d & 7) ^ ((d >> 3) & 7);
            lds[12288 + nxt*4096 + d*64 + ch*8 + (vr & 7)] = vv[j];
          }
        }
      }
      __syncthreads();
    }

    // ---- epilogue: li relayout + normalize + store
    float li0 = __shfl(li, g*4 + 0, 64);
    float li1 = __shfl(li, g*4 + 1, 64);
    float li2 = __shfl(li, g*4 + 2, 64);
    float li3 = __shfl(li, g*4 + 3, 64);
    float n0r = 1.f / li0, n1r = 1.f / li1, n2r = 1.f / li2, n3r = 1.f / li3;
#pragma unroll
    for (int df = 0; df < 4; ++df) {
      int row = qw0 + g*4;
      int col = h*64 + df*16 + c;
      size_t rb = ((size_t)b*2048 + row)*1024 + col;
      AO[rb]        = f2bf(o[df][0] * n0r);
      AO[rb + 1024] = f2bf(o[df][1] * n1r);
      AO[rb + 2048] = f2bf(o[df][2] * n2r);
      AO[rb + 3072] = f2bf(o[df][3] * n3r);
    }
  }
}

// ---------------------------------------------------------------------------------------
extern "C" void kernel_launch(void* const* d_in, const int* in_sizes, int n_in,
                              void* d_out, int out_size, void* d_ws, size_t ws_size,
                              hipStream_t stream)
{
  const float* q  = (const float*)d_in[0];
  const float* k  = (const float*)d_in[1];
  const float* v  = (const float*)d_in[2];
  // d_in[3] = mask (causal tril; applied analytically)
  const float* Wq = (const float*)d_in[4];
  const float* bq = (const float*)d_in[5];
  const float* Wk = (const float*)d_in[6];
  const float* bk = (const float*)d_in[7];
  const float* Wv = (const float*)d_in[8];
  const float* bv = (const float*)d_in[9];
  const float* Wo = (const float*)d_in[10];
  const float* bo = (const float*)d_in[11];
  float* out = (float*)d_out;

  u16* ws  = (u16*)d_ws;
  u16* qb   = ws;                 // [3][4096][1024] bf16 inputs (q,k,v contiguous)
  u16* Wqb  = ws + 12582912;      // [3][1024][1024] bf16 weights (Wq,Wk,Wv contiguous)
  u16* Wob  = ws + 15728640;      // [1024][1024]
  u16* QKVp = ws + 16777216;      // [4096][3072]
  u16* AO   = ws + 29360128;      // [4096][1024]  (total 64 MB exactly)

  convert_all<<<8192, 256, 0, stream>>>(q, k, v, Wq, Wk, Wv, Wo, qb);

  dim3 gq(48, 32);
  gemm_qkv<<<gq, 256, 0, stream>>>(qb, Wqb, bq, bk, bv, QKVp);

  dim3 ga(16, 16, 2);
  attn_fwd<<<ga, 256, 0, stream>>>(QKVp, AO);

  dim3 g1(16, 32);
  gemm_out<<<g1, 256, 0, stream>>>(AO, Wob, bo, out);
}

// Round 5
// 131.670 us; speedup vs baseline: 1.7340x; 1.0363x over previous
//
#include <hip/hip_runtime.h>

typedef unsigned int u32;
typedef unsigned short u16;
typedef __attribute__((ext_vector_type(8))) short bf16x8;
typedef __attribute__((ext_vector_type(8))) u16 u16x8;
typedef __attribute__((ext_vector_type(4))) u16 u16x4;
typedef __attribute__((ext_vector_type(4))) float f32x4;
typedef __attribute__((ext_vector_type(2))) u32 u32x2;

#define AS1 __attribute__((address_space(1)))
#define AS3 __attribute__((address_space(3)))

__device__ __forceinline__ void gload_lds16(const void* g, void* l) {
  __builtin_amdgcn_global_load_lds((const AS1 u32*)g, (AS3 u32*)l, 16, 0, 0);
}

__device__ __forceinline__ u16 f2bf(float f) {
  union { float f; u32 u; } x; x.f = f;
  u32 u = x.u;
  return (u16)((u + 0x7fffu + ((u >> 16) & 1u)) >> 16);
}

__device__ __forceinline__ u32 cvt_pk_bf16(float lo, float hi) {
  u32 r;
  asm("v_cvt_pk_bf16_f32 %0, %1, %2" : "=v"(r) : "v"(lo), "v"(hi));
  return r;
}

// ---------------- convert fp32 -> bf16 (q,k,v,Wq,Wk,Wv,Wo packed contiguously) ---------
__global__ __launch_bounds__(256) void convert_all(
    const float* __restrict__ q, const float* __restrict__ k, const float* __restrict__ v,
    const float* __restrict__ wq, const float* __restrict__ wk,
    const float* __restrict__ wv, const float* __restrict__ wo,
    u16* __restrict__ dst)
{
  int b = blockIdx.x, t = threadIdx.x;
  const float* sp; size_t lb;
  if (b < 6144) {
    sp = (b < 2048) ? q : ((b < 4096) ? k : v);
    lb = (size_t)(b & 2047) * 2048;
  } else {
    int w = (b - 6144) >> 9;
    sp = (w == 0) ? wq : ((w == 1) ? wk : ((w == 2) ? wv : wo));
    lb = (size_t)((b - 6144) & 511) * 2048;
  }
  lb += (size_t)t * 8;
  f32x4 f0 = *(const f32x4*)(sp + lb);
  f32x4 f1 = *(const f32x4*)(sp + lb + 4);
  u16x8 o;
  o[0]=f2bf(f0[0]); o[1]=f2bf(f0[1]); o[2]=f2bf(f0[2]); o[3]=f2bf(f0[3]);
  o[4]=f2bf(f1[0]); o[5]=f2bf(f1[1]); o[6]=f2bf(f1[2]); o[7]=f2bf(f1[3]);
  *(u16x8*)(dst + (size_t)b*2048 + (size_t)t*8) = o;
}

// ---------------- fused QKV GEMM ------------------------------------------------------
// Q,K -> Cqk[4096][2048] interleaved (Q at +0, K at +1024).
// V   -> VT[b][h][dh][s] transposed bf16 (packed 8B stores along s).
__global__ __launch_bounds__(256) void gemm_qkv(
    const u16* __restrict__ Xall,   // [3][4096][1024] bf16 (q,k,v)
    const u16* __restrict__ Wall,   // [3][1024][1024] bf16 (Wq,Wk,Wv)
    const float* __restrict__ bq, const float* __restrict__ bk, const float* __restrict__ bv,
    u16* __restrict__ Cqk, u16* __restrict__ VT)
{
  __shared__ __align__(16) u16 As[128*64];
  __shared__ __align__(16) u16 Bs[64*64];
  const int t = threadIdx.x;
  const int wid = t >> 6, l = t & 63;
  const int l4 = l >> 4, l15 = l & 15;
  const int n0g = blockIdx.x * 64;
  const int which = n0g >> 10;
  const int n0 = n0g & 1023;
  const u16* A  = Xall + (size_t)which * 4194304;
  const u16* Bw = Wall + (size_t)which * 1048576;
  const float* bias = (which == 0) ? bq : ((which == 1) ? bk : bv);
  const int m0 = blockIdx.y * 128;
  const int wr = wid >> 1, wc = wid & 1;
  const int arow = t >> 3, achk = t & 7;

  f32x4 acc[4][2] = {};

  for (int k0 = 0; k0 < 1024; k0 += 64) {
    __syncthreads();
#pragma unroll
    for (int i = 0; i < 4; ++i) {
      int row = i*32 + arow;
      gload_lds16(A + (size_t)(m0+row)*1024 + k0 + ((achk ^ (row&7)) << 3),
                  &As[i*2048 + wid*512]);
    }
#pragma unroll
    for (int i = 0; i < 2; ++i) {
      int row = i*32 + arow;
      gload_lds16(Bw + (size_t)(n0+row)*1024 + k0 + ((achk ^ (row&7)) << 3),
                  &Bs[i*2048 + wid*512]);
    }
    __syncthreads();
#pragma unroll
    for (int kh = 0; kh < 2; ++kh) {
      bf16x8 af[4], bf[2];
#pragma unroll
      for (int mf = 0; mf < 4; ++mf) {
        int row = wr*64 + mf*16 + l15;
        int ch = (kh*4 + l4) ^ (row & 7);
        af[mf] = *(const bf16x8*)&As[row*64 + ch*8];
      }
#pragma unroll
      for (int nf = 0; nf < 2; ++nf) {
        int row = wc*32 + nf*16 + l15;
        int ch = (kh*4 + l4) ^ (row & 7);
        bf[nf] = *(const bf16x8*)&Bs[row*64 + ch*8];
      }
#pragma unroll
      for (int mf = 0; mf < 4; ++mf)
#pragma unroll
        for (int nf = 0; nf < 2; ++nf)
          acc[mf][nf] = __builtin_amdgcn_mfma_f32_16x16x32_bf16(af[mf], bf[nf], acc[mf][nf], 0, 0, 0);
    }
  }
  if (which < 2) {
#pragma unroll
    for (int mf = 0; mf < 4; ++mf)
#pragma unroll
      for (int nf = 0; nf < 2; ++nf) {
        int row = m0 + wr*64 + mf*16 + l4*4;
        int col = n0 + wc*32 + nf*16 + l15;
        float bv = bias[col];
        int colg = which*1024 + col;
#pragma unroll
        for (int r = 0; r < 4; ++r)
          Cqk[(size_t)(row+r)*2048 + colg] = f2bf(acc[mf][nf][r] + bv);
      }
  } else {
#pragma unroll
    for (int mf = 0; mf < 4; ++mf)
#pragma unroll
      for (int nf = 0; nf < 2; ++nf) {
        int row = m0 + wr*64 + mf*16 + l4*4;
        int col = n0 + wc*32 + nf*16 + l15;
        float bv = bias[col];
        int bb = row >> 11, s = row & 2047;
        int hh = col >> 6, dh = col & 63;
        u16x4 pk;
#pragma unroll
        for (int r = 0; r < 4; ++r) pk[r] = f2bf(acc[mf][nf][r] + bv);
        *(u16x4*)&VT[((size_t)(((bb<<4)+hh)<<6) + dh)*2048 + s] = pk;
      }
  }
}

// ---------------- GEMM: out = AO * Wo^T + bo, fp32 out --------------------------------
__global__ __launch_bounds__(256) void gemm_out(
    const u16* __restrict__ A, const u16* __restrict__ Bw,
    const float* __restrict__ bias, float* __restrict__ C)
{
  __shared__ __align__(16) u16 As[128*64];
  __shared__ __align__(16) u16 Bs[64*64];
  const int t = threadIdx.x;
  const int wid = t >> 6, l = t & 63;
  const int l4 = l >> 4, l15 = l & 15;
  const int m0 = blockIdx.y * 128, n0 = blockIdx.x * 64;
  const int wr = wid >> 1, wc = wid & 1;
  const int arow = t >> 3, achk = t & 7;

  f32x4 acc[4][2] = {};

  for (int k0 = 0; k0 < 1024; k0 += 64) {
    __syncthreads();
#pragma unroll
    for (int i = 0; i < 4; ++i) {
      int row = i*32 + arow;
      gload_lds16(A + (size_t)(m0+row)*1024 + k0 + ((achk ^ (row&7)) << 3),
                  &As[i*2048 + wid*512]);
    }
#pragma unroll
    for (int i = 0; i < 2; ++i) {
      int row = i*32 + arow;
      gload_lds16(Bw + (size_t)(n0+row)*1024 + k0 + ((achk ^ (row&7)) << 3),
                  &Bs[i*2048 + wid*512]);
    }
    __syncthreads();
#pragma unroll
    for (int kh = 0; kh < 2; ++kh) {
      bf16x8 af[4], bf[2];
#pragma unroll
      for (int mf = 0; mf < 4; ++mf) {
        int row = wr*64 + mf*16 + l15;
        int ch = (kh*4 + l4) ^ (row & 7);
        af[mf] = *(const bf16x8*)&As[row*64 + ch*8];
      }
#pragma unroll
      for (int nf = 0; nf < 2; ++nf) {
        int row = wc*32 + nf*16 + l15;
        int ch = (kh*4 + l4) ^ (row & 7);
        bf[nf] = *(const bf16x8*)&Bs[row*64 + ch*8];
      }
#pragma unroll
      for (int mf = 0; mf < 4; ++mf)
#pragma unroll
        for (int nf = 0; nf < 2; ++nf)
          acc[mf][nf] = __builtin_amdgcn_mfma_f32_16x16x32_bf16(af[mf], bf[nf], acc[mf][nf], 0, 0, 0);
    }
  }
#pragma unroll
  for (int mf = 0; mf < 4; ++mf)
#pragma unroll
    for (int nf = 0; nf < 2; ++nf) {
      int row = m0 + wr*64 + mf*16 + l4*4;
      int col = n0 + wc*32 + nf*16 + l15;
      float bv = bias[col];
#pragma unroll
      for (int r = 0; r < 4; ++r)
        C[(size_t)(row+r)*1024 + col] = acc[mf][nf][r] + bv;
    }
}

// ---------------- causal flash attention, DH=64, QBLK=64, KVBLK=64 ---------------------
// Block p handles q-tile pair {p, 31-p} (uniform 33 KV-iters under any mapping).
// Swapped QK^T; V pre-transposed globally -> K and V^T both staged via global_load_lds.
// Depth-2 prefetch: 4 K-buffers + 4 V-buffers, counted vmcnt(8/4/0) + raw s_barrier.
__global__ __launch_bounds__(256) void attn_fwd(
    const u16* __restrict__ QK, const u16* __restrict__ VT, u16* __restrict__ AO)
{
  // u16 units: [0,4096) Q staging / per-wave P regions
  // [4096,20480) K bufs x4; [20480,36864) V^T bufs x4.  72 KB.
  __shared__ __align__(16) u16 lds[36864];
  const int t = threadIdx.x;
  const int wid = t >> 6, l = t & 63;
  const int g = l >> 4, c = l & 15;
  const int h = blockIdx.y, b = blockIdx.z;
  const u16* Qg  = QK + (size_t)b * 2048 * 2048 + (size_t)h * 64;
  const u16* Kg  = Qg + 1024;
  const u16* VTg = VT + (size_t)(((b << 4) + h) << 6) * 2048;
  const int arow = t >> 3, achk = t & 7;
  const float SC = 0.18033688f;  // (1/8) * log2(e)
  const int pbase = wid * 1024;
  const int cs = (c & 7) ^ ((c >> 3) << 2);

#define STAGE_KV(j) do { \
    const int bj_ = (j) & 3; const int kk0_ = (j) * 64; \
    _Pragma("unroll") \
    for (int ii = 0; ii < 2; ++ii) { \
      int row = ii*32 + arow; \
      gload_lds16(Kg + (size_t)(kk0_+row)*2048 + ((achk ^ (row&7)) << 3), \
                  &lds[4096 + bj_*4096 + ii*2048 + wid*512]); \
    } \
    _Pragma("unroll") \
    for (int ii = 0; ii < 2; ++ii) { \
      int row = ii*32 + arow; \
      gload_lds16(VTg + (size_t)row*2048 + kk0_ + ((achk ^ (row&7)) << 3), \
                  &lds[20480 + bj_*4096 + ii*2048 + wid*512]); \
    } \
  } while (0)

  for (int half = 0; half < 2; ++half) {
    const int qt = half ? (31 - (int)blockIdx.x) : (int)blockIdx.x;
    const int q0 = qt * 64;
    const int qw0 = q0 + wid * 16;

    __builtin_amdgcn_s_barrier();   // all waves done reading Q/P region of prev half
    // issue Q staging
#pragma unroll
    for (int i = 0; i < 2; ++i) {
      int row = i*32 + arow;
      gload_lds16(Qg + (size_t)(q0+row)*2048 + ((achk ^ (row&7)) << 3),
                  &lds[i*2048 + wid*512]);
    }
    STAGE_KV(0);
    if (qt >= 1) {
      STAGE_KV(1);
      asm volatile("s_waitcnt vmcnt(8)" ::: "memory");   // drain Q (+older)
    } else {
      asm volatile("s_waitcnt vmcnt(4)" ::: "memory");   // drain Q
    }
    __builtin_amdgcn_s_barrier();
    __builtin_amdgcn_sched_barrier(0);

    bf16x8 qf[2];
#pragma unroll
    for (int kh = 0; kh < 2; ++kh) {
      int row = wid*16 + c;
      int ch = (kh*4 + g) ^ (row & 7);
      qf[kh] = *(const bf16x8*)&lds[row*64 + ch*8];
    }

    float mi = -INFINITY, li = 0.f;
    f32x4 o[4] = {};

    for (int i = 0; i <= qt; ++i) {
      if (i + 2 <= qt) STAGE_KV(i + 2);
      if (i + 2 <= qt)      asm volatile("s_waitcnt vmcnt(8)" ::: "memory");
      else if (i + 1 <= qt) asm volatile("s_waitcnt vmcnt(4)" ::: "memory");
      else                  asm volatile("s_waitcnt vmcnt(0)" ::: "memory");
      __builtin_amdgcn_s_barrier();
      __builtin_amdgcn_sched_barrier(0);

      const u16* Kb = &lds[4096  + (i & 3) * 4096];
      const u16* Vb = &lds[20480 + (i & 3) * 4096];

      // QK^T swapped: lane holds q = c, k = 16nf + 4g + r
      f32x4 sT[4] = {};
#pragma unroll
      for (int kh = 0; kh < 2; ++kh) {
        bf16x8 kf[4];
#pragma unroll
        for (int nf = 0; nf < 4; ++nf) {
          int row = nf*16 + c;
          int ch = (kh*4 + g) ^ (c & 7);
          kf[nf] = *(const bf16x8*)&Kb[row*64 + ch*8];
        }
#pragma unroll
        for (int nf = 0; nf < 4; ++nf)
          sT[nf] = __builtin_amdgcn_mfma_f32_16x16x32_bf16(kf[nf], qf[kh], sT[nf], 0,0,0);
      }

      if (i == qt) {              // diagonal causal mask (peeled)
#pragma unroll
        for (int nf = 0; nf < 4; ++nf)
#pragma unroll
          for (int r = 0; r < 4; ++r)
            if (nf*16 + g*4 + r > wid*16 + c) sT[nf][r] = -INFINITY;
      }

      // online softmax: lane-local reduce + 2 shuffles
      float mx = fmaxf(fmaxf(sT[0][0], sT[0][1]), fmaxf(sT[0][2], sT[0][3]));
#pragma unroll
      for (int nf = 1; nf < 4; ++nf)
        mx = fmaxf(mx, fmaxf(fmaxf(sT[nf][0], sT[nf][1]), fmaxf(sT[nf][2], sT[nf][3])));
      mx = fmaxf(mx, __shfl_xor(mx, 16, 64));
      mx = fmaxf(mx, __shfl_xor(mx, 32, 64));
      float mn = fmaxf(mi, mx * SC);
      float corr = exp2f(mi - mn);
      float sum = 0.f;
#pragma unroll
      for (int nf = 0; nf < 4; ++nf)
#pragma unroll
        for (int r = 0; r < 4; ++r) {
          float pv = exp2f(fmaf(sT[nf][r], SC, -mn));
          sT[nf][r] = pv;
          sum += pv;
        }
      sum += __shfl_xor(sum, 16, 64);
      sum += __shfl_xor(sum, 32, 64);
      li = li * corr + sum;
      mi = mn;

      // corr relayout s-layout(q=c) -> o-layout(q=4g+r)
      float corr0 = __shfl(corr, g*4 + 0, 64);
      float corr1 = __shfl(corr, g*4 + 1, 64);
      float corr2 = __shfl(corr, g*4 + 2, 64);
      float corr3 = __shfl(corr, g*4 + 3, 64);
#pragma unroll
      for (int df = 0; df < 4; ++df) {
        o[df][0] *= corr0; o[df][1] *= corr1;
        o[df][2] *= corr2; o[df][3] *= corr3;
      }

      // P -> LDS (wave-private), packed bf16 via cvt_pk + b64 writes
#pragma unroll
      for (int nf = 0; nf < 4; ++nf) {
        u32x2 w;
        w[0] = cvt_pk_bf16(sT[nf][0], sT[nf][1]);
        w[1] = cvt_pk_bf16(sT[nf][2], sT[nf][3]);
        int ch = (2*nf + (g >> 1)) ^ cs;
        *(u32x2*)&lds[pbase + c*64 + ch*8 + (g & 1)*4] = w;
      }
      asm volatile("s_waitcnt lgkmcnt(0)" ::: "memory");
      __builtin_amdgcn_sched_barrier(0);

      // PV
#pragma unroll
      for (int kh = 0; kh < 2; ++kh) {
        bf16x8 pfr, vf[4];
        {
          int ch = (kh*4 + g) ^ cs;
          pfr = *(const bf16x8*)&lds[pbase + c*64 + ch*8];
        }
#pragma unroll
        for (int df = 0; df < 4; ++df) {
          int d = df*16 + c;
          int ch = (kh*4 + g) ^ (d & 7);
          vf[df] = *(const bf16x8*)&Vb[d*64 + ch*8];
        }
#pragma unroll
        for (int df = 0; df < 4; ++df)
          o[df] = __builtin_amdgcn_mfma_f32_16x16x32_bf16(pfr, vf[df], o[df], 0,0,0);
      }
    }

    // epilogue: li relayout + normalize + store
    float li0 = __shfl(li, g*4 + 0, 64);
    float li1 = __shfl(li, g*4 + 1, 64);
    float li2 = __shfl(li, g*4 + 2, 64);
    float li3 = __shfl(li, g*4 + 3, 64);
    float n0r = 1.f / li0, n1r = 1.f / li1, n2r = 1.f / li2, n3r = 1.f / li3;
#pragma unroll
    for (int df = 0; df < 4; ++df) {
      int row = qw0 + g*4;
      int col = h*64 + df*16 + c;
      size_t rb = ((size_t)b*2048 + row)*1024 + col;
      AO[rb]        = f2bf(o[df][0] * n0r);
      AO[rb + 1024] = f2bf(o[df][1] * n1r);
      AO[rb + 2048] = f2bf(o[df][2] * n2r);
      AO[rb + 3072] = f2bf(o[df][3] * n3r);
    }
  }
#undef STAGE_KV
}

// ---------------------------------------------------------------------------------------
extern "C" void kernel_launch(void* const* d_in, const int* in_sizes, int n_in,
                              void* d_out, int out_size, void* d_ws, size_t ws_size,
                              hipStream_t stream)
{
  const float* q  = (const float*)d_in[0];
  const float* k  = (const float*)d_in[1];
  const float* v  = (const float*)d_in[2];
  // d_in[3] = mask (causal tril; applied analytically)
  const float* Wq = (const float*)d_in[4];
  const float* bq = (const float*)d_in[5];
  const float* Wk = (const float*)d_in[6];
  const float* bk = (const float*)d_in[7];
  const float* Wv = (const float*)d_in[8];
  const float* bv = (const float*)d_in[9];
  const float* Wo = (const float*)d_in[10];
  const float* bo = (const float*)d_in[11];
  float* out = (float*)d_out;

  u16* ws   = (u16*)d_ws;
  u16* qb   = ws;                 // [3][4096][1024] bf16 inputs (q,k,v)
  u16* Wqb  = ws + 12582912;      // [3][1024][1024] bf16 weights (Wq,Wk,Wv)
  u16* Wob  = ws + 15728640;      // [1024][1024]
  u16* QKp  = ws + 16777216;      // [4096][2048]  (Q | K)
  u16* VTp  = ws + 25165824;      // [2][16][64][2048]  V transposed
  u16* AO   = ws + 29360128;      // [4096][1024]   (total = 64 MB exactly)

  convert_all<<<8192, 256, 0, stream>>>(q, k, v, Wq, Wk, Wv, Wo, qb);

  dim3 gq(48, 32);
  gemm_qkv<<<gq, 256, 0, stream>>>(qb, Wqb, bq, bk, bv, QKp, VTp);

  dim3 ga(16, 16, 2);
  attn_fwd<<<ga, 256, 0, stream>>>(QKp, VTp, AO);

  dim3 g1(16, 32);
  gemm_out<<<g1, 256, 0, stream>>>(AO, Wob, bo, out);
}

// Round 6
// 126.055 us; speedup vs baseline: 1.8113x; 1.0445x over previous
//
#include <hip/hip_runtime.h>

typedef unsigned int u32;
typedef unsigned short u16;
typedef __attribute__((ext_vector_type(8))) short bf16x8;
typedef __attribute__((ext_vector_type(8))) u16 u16x8;
typedef __attribute__((ext_vector_type(4))) u16 u16x4;
typedef __attribute__((ext_vector_type(4))) float f32x4;
typedef __attribute__((ext_vector_type(2))) u32 u32x2;

#define AS1 __attribute__((address_space(1)))
#define AS3 __attribute__((address_space(3)))

__device__ __forceinline__ void gload_lds16(const void* g, void* l) {
  __builtin_amdgcn_global_load_lds((const AS1 u32*)g, (AS3 u32*)l, 16, 0, 0);
}

__device__ __forceinline__ u16 f2bf(float f) {
  union { float f; u32 u; } x; x.f = f;
  u32 u = x.u;
  return (u16)((u + 0x7fffu + ((u >> 16) & 1u)) >> 16);
}

__device__ __forceinline__ u32 cvt_pk_bf16(float lo, float hi) {
  u32 r;
  asm("v_cvt_pk_bf16_f32 %0, %1, %2" : "=v"(r) : "v"(lo), "v"(hi));
  return r;
}

// ---------------- convert fp32 -> bf16 (q,k,v,Wq,Wk,Wv,Wo packed contiguously) ---------
__global__ __launch_bounds__(256) void convert_all(
    const float* __restrict__ q, const float* __restrict__ k, const float* __restrict__ v,
    const float* __restrict__ wq, const float* __restrict__ wk,
    const float* __restrict__ wv, const float* __restrict__ wo,
    u16* __restrict__ dst)
{
  int b = blockIdx.x, t = threadIdx.x;
  const float* sp; size_t lb;
  if (b < 6144) {
    sp = (b < 2048) ? q : ((b < 4096) ? k : v);
    lb = (size_t)(b & 2047) * 2048;
  } else {
    int w = (b - 6144) >> 9;
    sp = (w == 0) ? wq : ((w == 1) ? wk : ((w == 2) ? wv : wo));
    lb = (size_t)((b - 6144) & 511) * 2048;
  }
  lb += (size_t)t * 8;
  f32x4 f0 = *(const f32x4*)(sp + lb);
  f32x4 f1 = *(const f32x4*)(sp + lb + 4);
  u16x8 o;
  o[0]=f2bf(f0[0]); o[1]=f2bf(f0[1]); o[2]=f2bf(f0[2]); o[3]=f2bf(f0[3]);
  o[4]=f2bf(f1[0]); o[5]=f2bf(f1[1]); o[6]=f2bf(f1[2]); o[7]=f2bf(f1[3]);
  *(u16x8*)(dst + (size_t)b*2048 + (size_t)t*8) = o;
}

// ---------------- fused QKV GEMM ------------------------------------------------------
// Q,K -> Cqk[4096][2048] interleaved (Q at +0, K at +1024).
// V   -> VT[b][h][dh][s] transposed bf16 (packed 8B stores along s).
__global__ __launch_bounds__(256) void gemm_qkv(
    const u16* __restrict__ Xall,   // [3][4096][1024] bf16 (q,k,v)
    const u16* __restrict__ Wall,   // [3][1024][1024] bf16 (Wq,Wk,Wv)
    const float* __restrict__ bq, const float* __restrict__ bk, const float* __restrict__ bv,
    u16* __restrict__ Cqk, u16* __restrict__ VT)
{
  __shared__ __align__(16) u16 As[128*64];
  __shared__ __align__(16) u16 Bs[64*64];
  const int t = threadIdx.x;
  const int wid = t >> 6, l = t & 63;
  const int l4 = l >> 4, l15 = l & 15;
  const int n0g = blockIdx.x * 64;
  const int which = n0g >> 10;
  const int n0 = n0g & 1023;
  const u16* A  = Xall + (size_t)which * 4194304;
  const u16* Bw = Wall + (size_t)which * 1048576;
  const float* bias = (which == 0) ? bq : ((which == 1) ? bk : bv);
  const int m0 = blockIdx.y * 128;
  const int wr = wid >> 1, wc = wid & 1;
  const int arow = t >> 3, achk = t & 7;

  f32x4 acc[4][2] = {};

  for (int k0 = 0; k0 < 1024; k0 += 64) {
    __syncthreads();
#pragma unroll
    for (int i = 0; i < 4; ++i) {
      int row = i*32 + arow;
      gload_lds16(A + (size_t)(m0+row)*1024 + k0 + ((achk ^ (row&7)) << 3),
                  &As[i*2048 + wid*512]);
    }
#pragma unroll
    for (int i = 0; i < 2; ++i) {
      int row = i*32 + arow;
      gload_lds16(Bw + (size_t)(n0+row)*1024 + k0 + ((achk ^ (row&7)) << 3),
                  &Bs[i*2048 + wid*512]);
    }
    __syncthreads();
#pragma unroll
    for (int kh = 0; kh < 2; ++kh) {
      bf16x8 af[4], bf[2];
#pragma unroll
      for (int mf = 0; mf < 4; ++mf) {
        int row = wr*64 + mf*16 + l15;
        int ch = (kh*4 + l4) ^ (row & 7);
        af[mf] = *(const bf16x8*)&As[row*64 + ch*8];
      }
#pragma unroll
      for (int nf = 0; nf < 2; ++nf) {
        int row = wc*32 + nf*16 + l15;
        int ch = (kh*4 + l4) ^ (row & 7);
        bf[nf] = *(const bf16x8*)&Bs[row*64 + ch*8];
      }
#pragma unroll
      for (int mf = 0; mf < 4; ++mf)
#pragma unroll
        for (int nf = 0; nf < 2; ++nf)
          acc[mf][nf] = __builtin_amdgcn_mfma_f32_16x16x32_bf16(af[mf], bf[nf], acc[mf][nf], 0, 0, 0);
    }
  }
  if (which < 2) {
#pragma unroll
    for (int mf = 0; mf < 4; ++mf)
#pragma unroll
      for (int nf = 0; nf < 2; ++nf) {
        int row = m0 + wr*64 + mf*16 + l4*4;
        int col = n0 + wc*32 + nf*16 + l15;
        float bv = bias[col];
        int colg = which*1024 + col;
#pragma unroll
        for (int r = 0; r < 4; ++r)
          Cqk[(size_t)(row+r)*2048 + colg] = f2bf(acc[mf][nf][r] + bv);
      }
  } else {
#pragma unroll
    for (int mf = 0; mf < 4; ++mf)
#pragma unroll
      for (int nf = 0; nf < 2; ++nf) {
        int row = m0 + wr*64 + mf*16 + l4*4;
        int col = n0 + wc*32 + nf*16 + l15;
        float bv = bias[col];
        int bb = row >> 11, s = row & 2047;
        int hh = col >> 6, dh = col & 63;
        u16x4 pk;
#pragma unroll
        for (int r = 0; r < 4; ++r) pk[r] = f2bf(acc[mf][nf][r] + bv);
        *(u16x4*)&VT[((size_t)(((bb<<4)+hh)<<6) + dh)*2048 + s] = pk;
      }
  }
}

// ---------------- GEMM: out = AO * Wo^T + bo, fp32 out --------------------------------
__global__ __launch_bounds__(256) void gemm_out(
    const u16* __restrict__ A, const u16* __restrict__ Bw,
    const float* __restrict__ bias, float* __restrict__ C)
{
  __shared__ __align__(16) u16 As[128*64];
  __shared__ __align__(16) u16 Bs[64*64];
  const int t = threadIdx.x;
  const int wid = t >> 6, l = t & 63;
  const int l4 = l >> 4, l15 = l & 15;
  const int m0 = blockIdx.y * 128, n0 = blockIdx.x * 64;
  const int wr = wid >> 1, wc = wid & 1;
  const int arow = t >> 3, achk = t & 7;

  f32x4 acc[4][2] = {};

  for (int k0 = 0; k0 < 1024; k0 += 64) {
    __syncthreads();
#pragma unroll
    for (int i = 0; i < 4; ++i) {
      int row = i*32 + arow;
      gload_lds16(A + (size_t)(m0+row)*1024 + k0 + ((achk ^ (row&7)) << 3),
                  &As[i*2048 + wid*512]);
    }
#pragma unroll
    for (int i = 0; i < 2; ++i) {
      int row = i*32 + arow;
      gload_lds16(Bw + (size_t)(n0+row)*1024 + k0 + ((achk ^ (row&7)) << 3),
                  &Bs[i*2048 + wid*512]);
    }
    __syncthreads();
#pragma unroll
    for (int kh = 0; kh < 2; ++kh) {
      bf16x8 af[4], bf[2];
#pragma unroll
      for (int mf = 0; mf < 4; ++mf) {
        int row = wr*64 + mf*16 + l15;
        int ch = (kh*4 + l4) ^ (row & 7);
        af[mf] = *(const bf16x8*)&As[row*64 + ch*8];
      }
#pragma unroll
      for (int nf = 0; nf < 2; ++nf) {
        int row = wc*32 + nf*16 + l15;
        int ch = (kh*4 + l4) ^ (row & 7);
        bf[nf] = *(const bf16x8*)&Bs[row*64 + ch*8];
      }
#pragma unroll
      for (int mf = 0; mf < 4; ++mf)
#pragma unroll
        for (int nf = 0; nf < 2; ++nf)
          acc[mf][nf] = __builtin_amdgcn_mfma_f32_16x16x32_bf16(af[mf], bf[nf], acc[mf][nf], 0, 0, 0);
    }
  }
#pragma unroll
  for (int mf = 0; mf < 4; ++mf)
#pragma unroll
    for (int nf = 0; nf < 2; ++nf) {
      int row = m0 + wr*64 + mf*16 + l4*4;
      int col = n0 + wc*32 + nf*16 + l15;
      float bv = bias[col];
#pragma unroll
      for (int r = 0; r < 4; ++r)
        C[(size_t)(row+r)*1024 + col] = acc[mf][nf][r] + bv;
    }
}

// ---------------- causal flash attention, split-KV, DH=64, QBLK=64, KVBLK=64 -----------
// 1024 blocks: (p,s=0) = q-tile p final (p+1 iters) + q-tile 31-p partial over KV tiles
// 0..15-p (16-p iters) = 17 total; (p,s=1) = q-tile 31-p partial over KV 16-p..31-p (16).
// Uniform work under any block->CU mapping; 40KB LDS -> 4 blocks/CU = 4 waves/SIMD.
__device__ __forceinline__ void stage_kv(u16* lds, const u16* Kt, const u16* Vt,
                                         int buf, int wid) {
#pragma unroll
  for (int ii = 0; ii < 2; ++ii)
    gload_lds16(Kt + (size_t)ii*32*2048, &lds[4096 + buf*4096 + ii*2048 + wid*512]);
#pragma unroll
  for (int ii = 0; ii < 2; ++ii)
    gload_lds16(Vt + (size_t)ii*32*2048, &lds[12288 + buf*4096 + ii*2048 + wid*512]);
}

__device__ __forceinline__ void attn_phase(
    u16* lds, const u16* Qg, const u16* Ka, const u16* Va,
    int q0, int kt0, int nkv, bool maskLast,
    int wid, int g, int c, int arow, int achk, int pbase, int cs,
    float& MI, float& LI, f32x4 (&o)[4])
{
  const float SC = 0.18033688f;  // (1/8) * log2(e)
  // stage Q tile [64][64] swizzled
#pragma unroll
  for (int i = 0; i < 2; ++i) {
    int row = i*32 + arow;
    gload_lds16(Qg + (size_t)(q0+row)*2048 + ((achk ^ (row&7)) << 3),
                &lds[i*2048 + wid*512]);
  }
  const u16* Kt = Ka + (size_t)kt0 * (64*2048);
  const u16* Vt = Va + kt0 * 64;
  stage_kv(lds, Kt, Vt, 0, wid);
  asm volatile("s_waitcnt vmcnt(0)" ::: "memory");
  __builtin_amdgcn_s_barrier();
  __builtin_amdgcn_sched_barrier(0);

  bf16x8 qf[2];
#pragma unroll
  for (int kh = 0; kh < 2; ++kh) {
    int row = wid*16 + c;
    int ch = (kh*4 + g) ^ (row & 7);
    qf[kh] = *(const bf16x8*)&lds[row*64 + ch*8];
  }

  float mi = -INFINITY, li = 0.f;
#pragma unroll
  for (int df = 0; df < 4; ++df) o[df] = f32x4{0.f, 0.f, 0.f, 0.f};

  for (int i = 0; i < nkv; ++i) {
    if (i + 1 < nkv) {
      Kt += 64*2048; Vt += 64;
      stage_kv(lds, Kt, Vt, (i+1)&1, wid);
    }
    const u16* Kb = &lds[4096  + (i&1)*4096];
    const u16* Vb = &lds[12288 + (i&1)*4096];

    // QK^T swapped: lane holds q = c, k = 16nf + 4g + r
    f32x4 sT[4] = {};
#pragma unroll
    for (int kh = 0; kh < 2; ++kh) {
      bf16x8 kf[4];
#pragma unroll
      for (int nf = 0; nf < 4; ++nf) {
        int row = nf*16 + c;
        int ch = (kh*4 + g) ^ (c & 7);
        kf[nf] = *(const bf16x8*)&Kb[row*64 + ch*8];
      }
#pragma unroll
      for (int nf = 0; nf < 4; ++nf)
        sT[nf] = __builtin_amdgcn_mfma_f32_16x16x32_bf16(kf[nf], qf[kh], sT[nf], 0,0,0);
    }

    if (maskLast && i == nkv - 1) {   // diagonal causal mask
#pragma unroll
      for (int nf = 0; nf < 4; ++nf)
#pragma unroll
        for (int r = 0; r < 4; ++r)
          if (nf*16 + g*4 + r > wid*16 + c) sT[nf][r] = -INFINITY;
    }

    // online softmax: lane-local reduce + 2 shuffles
    float mx = fmaxf(fmaxf(sT[0][0], sT[0][1]), fmaxf(sT[0][2], sT[0][3]));
#pragma unroll
    for (int nf = 1; nf < 4; ++nf)
      mx = fmaxf(mx, fmaxf(fmaxf(sT[nf][0], sT[nf][1]), fmaxf(sT[nf][2], sT[nf][3])));
    mx = fmaxf(mx, __shfl_xor(mx, 16, 64));
    mx = fmaxf(mx, __shfl_xor(mx, 32, 64));
    float mn = fmaxf(mi, mx * SC);
    float corr = exp2f(mi - mn);
    float sum = 0.f;
#pragma unroll
    for (int nf = 0; nf < 4; ++nf)
#pragma unroll
      for (int r = 0; r < 4; ++r) {
        float pv = exp2f(fmaf(sT[nf][r], SC, -mn));
        sT[nf][r] = pv;
        sum += pv;
      }
    sum += __shfl_xor(sum, 16, 64);
    sum += __shfl_xor(sum, 32, 64);
    li = li * corr + sum;
    mi = mn;

    // corr relayout s-layout(q=c) -> o-layout(q=4g+r)
    float corr0 = __shfl(corr, g*4 + 0, 64);
    float corr1 = __shfl(corr, g*4 + 1, 64);
    float corr2 = __shfl(corr, g*4 + 2, 64);
    float corr3 = __shfl(corr, g*4 + 3, 64);
#pragma unroll
    for (int df = 0; df < 4; ++df) {
      o[df][0] *= corr0; o[df][1] *= corr1;
      o[df][2] *= corr2; o[df][3] *= corr3;
    }

    // P -> LDS (wave-private), packed bf16 via cvt_pk + b64 writes
#pragma unroll
    for (int nf = 0; nf < 4; ++nf) {
      u32x2 w;
      w[0] = cvt_pk_bf16(sT[nf][0], sT[nf][1]);
      w[1] = cvt_pk_bf16(sT[nf][2], sT[nf][3]);
      int ch = (2*nf + (g >> 1)) ^ cs;
      *(u32x2*)&lds[pbase + c*64 + ch*8 + (g & 1)*4] = w;
    }
    asm volatile("s_waitcnt lgkmcnt(0)" ::: "memory");
    __builtin_amdgcn_sched_barrier(0);

    // PV
#pragma unroll
    for (int kh = 0; kh < 2; ++kh) {
      bf16x8 pfr, vf[4];
      {
        int ch = (kh*4 + g) ^ cs;
        pfr = *(const bf16x8*)&lds[pbase + c*64 + ch*8];
      }
#pragma unroll
      for (int df = 0; df < 4; ++df) {
        int d = df*16 + c;
        int ch = (kh*4 + g) ^ (d & 7);
        vf[df] = *(const bf16x8*)&Vb[d*64 + ch*8];
      }
#pragma unroll
      for (int df = 0; df < 4; ++df)
        o[df] = __builtin_amdgcn_mfma_f32_16x16x32_bf16(pfr, vf[df], o[df], 0,0,0);
    }

    asm volatile("s_waitcnt vmcnt(0)" ::: "memory");  // next K/V tile landed
    __builtin_amdgcn_s_barrier();                     // all done reading cur bufs
    __builtin_amdgcn_sched_barrier(0);
  }
  MI = mi; LI = li;
}

__device__ __forceinline__ void store_partial(
    float* __restrict__ part, int b, int h, int p, int s,
    int wid, int g, int c, float mi, float li, const f32x4 (&o)[4])
{
  float m0 = __shfl(mi, g*4 + 0, 64), m1 = __shfl(mi, g*4 + 1, 64);
  float m2 = __shfl(mi, g*4 + 2, 64), m3 = __shfl(mi, g*4 + 3, 64);
  float l0 = __shfl(li, g*4 + 0, 64), l1 = __shfl(li, g*4 + 1, 64);
  float l2 = __shfl(li, g*4 + 2, 64), l3 = __shfl(li, g*4 + 3, 64);
  float* po = part + (size_t)((((b*16 + h)*16 + p)*2 + s)) * 4224;
  int rl = wid*16 + g*4;
#pragma unroll
  for (int df = 0; df < 4; ++df) {
    int col = df*16 + c;
    po[(rl+0)*64 + col] = o[df][0];
    po[(rl+1)*64 + col] = o[df][1];
    po[(rl+2)*64 + col] = o[df][2];
    po[(rl+3)*64 + col] = o[df][3];
  }
  if (c == 0) {
    po[4096 + rl+0] = m0; po[4096 + rl+1] = m1;
    po[4096 + rl+2] = m2; po[4096 + rl+3] = m3;
    po[4160 + rl+0] = l0; po[4160 + rl+1] = l1;
    po[4160 + rl+2] = l2; po[4160 + rl+3] = l3;
  }
}

__global__ __launch_bounds__(256, 4) void attn_fwd(
    const u16* __restrict__ QK, const u16* __restrict__ VT,
    u16* __restrict__ AO, float* __restrict__ part)
{
  // u16 units: [0,4096) Q staging / per-wave P; [4096,12288) K dbuf; [12288,20480) V dbuf
  __shared__ __align__(16) u16 lds[20480];
  const int t = threadIdx.x;
  const int wid = t >> 6, l = t & 63;
  const int g = l >> 4, c = l & 15;
  const int gx = blockIdx.x, h = blockIdx.y, b = blockIdx.z;
  const int p = gx >> 1, s = gx & 1;
  const u16* Qg  = QK + (size_t)b * 2048 * 2048 + (size_t)h * 64;
  const u16* Kg  = Qg + 1024;
  const u16* VTg = VT + (size_t)(((b << 4) + h) << 6) * 2048;
  const int arow = t >> 3, achk = t & 7;
  const int pbase = wid * 1024;
  const int cs = (c & 7) ^ ((c >> 3) << 2);
  const u16* Ka = Kg  + (size_t)arow*2048 + ((achk ^ (arow & 7)) << 3);
  const u16* Va = VTg + (size_t)arow*2048 + ((achk ^ (arow & 7)) << 3);

  float mi, li; f32x4 o[4];

  if (s == 0) {
    // phase A: q-tile p, KV 0..p, final output
    attn_phase(lds, Qg, Ka, Va, p*64, 0, p+1, true,
               wid, g, c, arow, achk, pbase, cs, mi, li, o);
    {
      float li0 = __shfl(li, g*4 + 0, 64);
      float li1 = __shfl(li, g*4 + 1, 64);
      float li2 = __shfl(li, g*4 + 2, 64);
      float li3 = __shfl(li, g*4 + 3, 64);
      float n0r = 1.f/li0, n1r = 1.f/li1, n2r = 1.f/li2, n3r = 1.f/li3;
      int row = p*64 + wid*16 + g*4;
#pragma unroll
      for (int df = 0; df < 4; ++df) {
        int col = h*64 + df*16 + c;
        size_t rb = ((size_t)b*2048 + row)*1024 + col;
        AO[rb]        = f2bf(o[df][0] * n0r);
        AO[rb + 1024] = f2bf(o[df][1] * n1r);
        AO[rb + 2048] = f2bf(o[df][2] * n2r);
        AO[rb + 3072] = f2bf(o[df][3] * n3r);
      }
    }
    // phase B: q-tile 31-p, KV tiles 0..15-p, partial slot 0
    attn_phase(lds, Qg, Ka, Va, (31-p)*64, 0, 16-p, false,
               wid, g, c, arow, achk, pbase, cs, mi, li, o);
    store_partial(part, b, h, p, 0, wid, g, c, mi, li, o);
  } else {
    // q-tile 31-p, KV tiles 16-p..31-p (incl. diagonal), partial slot 1
    attn_phase(lds, Qg, Ka, Va, (31-p)*64, 16-p, 16, true,
               wid, g, c, arow, achk, pbase, cs, mi, li, o);
    store_partial(part, b, h, p, 1, wid, g, c, mi, li, o);
  }
}

// ---------------- merge the two partials of q-tiles 16..31 -----------------------------
__global__ __launch_bounds__(256) void attn_merge(
    const float* __restrict__ part, u16* __restrict__ AO)
{
  int slot = blockIdx.x;            // ((b*16+h)*16+p)
  int p = slot & 15;
  int h = (slot >> 4) & 15;
  int b = slot >> 8;
  const float* p0 = part + (size_t)slot * 8448;
  const float* p1 = p0 + 4224;
  int t = threadIdx.x;
  int r = t >> 2, c0 = (t & 3) * 16;
  float m0 = p0[4096 + r], m1 = p1[4096 + r];
  float l0 = p0[4160 + r], l1 = p1[4160 + r];
  float m = fmaxf(m0, m1);
  float e0 = exp2f(m0 - m), e1 = exp2f(m1 - m);
  float rl = 1.f / (l0*e0 + l1*e1);
  e0 *= rl; e1 *= rl;
  const f32x4* a0 = (const f32x4*)(p0 + r*64 + c0);
  const f32x4* a1 = (const f32x4*)(p1 + r*64 + c0);
  u16x8 w0, w1;
#pragma unroll
  for (int q4 = 0; q4 < 4; ++q4) {
    f32x4 x = a0[q4], y = a1[q4];
#pragma unroll
    for (int j = 0; j < 4; ++j) {
      u16 bf = f2bf(x[j]*e0 + y[j]*e1);
      if (q4 < 2) w0[q4*4+j] = bf; else w1[(q4-2)*4+j] = bf;
    }
  }
  int qrow = (31 - p)*64 + r;
  size_t ab = ((size_t)b*2048 + qrow)*1024 + h*64 + c0;
  *(u16x8*)&AO[ab]     = w0;
  *(u16x8*)&AO[ab + 8] = w1;
}

// ---------------------------------------------------------------------------------------
extern "C" void kernel_launch(void* const* d_in, const int* in_sizes, int n_in,
                              void* d_out, int out_size, void* d_ws, size_t ws_size,
                              hipStream_t stream)
{
  const float* q  = (const float*)d_in[0];
  const float* k  = (const float*)d_in[1];
  const float* v  = (const float*)d_in[2];
  // d_in[3] = mask (causal tril; applied analytically)
  const float* Wq = (const float*)d_in[4];
  const float* bq = (const float*)d_in[5];
  const float* Wk = (const float*)d_in[6];
  const float* bk = (const float*)d_in[7];
  const float* Wv = (const float*)d_in[8];
  const float* bv = (const float*)d_in[9];
  const float* Wo = (const float*)d_in[10];
  const float* bo = (const float*)d_in[11];
  float* out = (float*)d_out;

  u16* ws   = (u16*)d_ws;
  u16* qb   = ws;                 // [3][4096][1024] bf16 inputs (dead after gemm_qkv;
                                  //  reused as f32 partial buffer by attn)
  u16* Wqb  = ws + 12582912;      // [3][1024][1024] bf16 weights (Wq,Wk,Wv)
  u16* Wob  = ws + 15728640;      // [1024][1024]
  u16* QKp  = ws + 16777216;      // [4096][2048]  (Q | K)
  u16* VTp  = ws + 25165824;      // [2][16][64][2048]  V transposed
  u16* AO   = ws + 29360128;      // [4096][1024]   (total = 64 MB exactly)

  convert_all<<<8192, 256, 0, stream>>>(q, k, v, Wq, Wk, Wv, Wo, qb);

  dim3 gq(48, 32);
  gemm_qkv<<<gq, 256, 0, stream>>>(qb, Wqb, bq, bk, bv, QKp, VTp);

  dim3 ga(32, 16, 2);
  attn_fwd<<<ga, 256, 0, stream>>>(QKp, VTp, AO, (float*)d_ws);

  attn_merge<<<512, 256, 0, stream>>>((const float*)d_ws, AO);

  dim3 g1(16, 32);
  gemm_out<<<g1, 256, 0, stream>>>(AO, Wob, bo, out);
}